// Round 6
// baseline (1662.194 us; speedup 1.0000x reference)
//
#include <hip/hip_runtime.h>
#include <math.h>

#define NN 50000
#define DD 128
#define ET_N 640000
#define EH_N 320000
#define NL 3

static inline int cdiv(int a, int b){ return (a+b-1)/b; }

typedef __attribute__((ext_vector_type(8))) short short8;
typedef __attribute__((ext_vector_type(4))) float f32x4;

// ---------------- compiled-in device scratch (no d_ws dependency) ----------------
__device__ float   g_h [(size_t)NN*DD];
__device__ unsigned short g_hb[(size_t)NN*DD];        // bf16 copy of h (GEMM A input)
__device__ unsigned short g_Wb[(size_t)NL*8*DD*DD];   // bf16, TRANSPOSED [n][k]; l*8 + {tQ,tK,tV,tS,hQ,hK,hV,hS}
__device__ float   g_Q [2][(size_t)NN*DD];
__device__ float   g_S [2][(size_t)NN*DD];
__device__ ushort2 g_KV[2][(size_t)NN*DD];   // .x = K bf16 bits, .y = V bf16 bits
__device__ int     g_cnt[2][NN];
__device__ int     g_cur[2][NN];
__device__ int     g_rs [2][NN+1];
__device__ int     g_srcc[2][ET_N];          // CSR-ordered src (conv1 uses first EH_N)
__device__ float   g_ta[ET_N];               // CSR-ordered temporal attr (scalar)
__device__ float4  g_ha[EH_N];               // CSR-ordered host attr (3 used)

__device__ inline unsigned short f2bf(float f){
  unsigned u = __float_as_uint(f);
  unsigned r = (u + 0x7fffu + ((u>>16)&1u)) >> 16;   // RNE
  return (unsigned short)r;
}
__device__ inline float bf2f(unsigned short s){
  return __uint_as_float(((unsigned)s)<<16);
}

// ---------------- tiny helpers ----------------
__global__ void k_copy_h(const float* __restrict__ x){
  int i = blockIdx.x*256 + threadIdx.x;           // float4 index
  if (i < NN*DD/4){
    float4 v = reinterpret_cast<const float4*>(x)[i];
    reinterpret_cast<float4*>(g_h)[i] = v;
    ushort4 b; b.x=f2bf(v.x); b.y=f2bf(v.y); b.z=f2bf(v.z); b.w=f2bf(v.w);
    reinterpret_cast<ushort4*>(g_hb)[i] = b;
  }
}

__global__ void k_zero_cnt(){
  int i = blockIdx.x*256 + threadIdx.x;
  if (i < NN) g_cnt[blockIdx.y][i] = 0;
}

// convert + transpose conv weights to bf16 [n][k]
struct WPtrs { const float* W[24]; };
__global__ __launch_bounds__(256) void k_cvtw(WPtrs wp){
  int mat = blockIdx.y;                    // 0..23  (= l*8 + set)
  const float* W = wp.W[mat];
  int e = blockIdx.x*256 + threadIdx.x;    // output index, 0..16383
  int n = e >> 7, k = e & 127;
  g_Wb[(size_t)mat*DD*DD + e] = f2bf(W[k*DD+n]);
}

// ---------- CSR build (by destination) ----------
__global__ void k_hist(const int* __restrict__ dstT, const int* __restrict__ dstH){
  int which = blockIdx.y;
  int E = which ? EH_N : ET_N;
  const int* dst = which ? dstH : dstT;
  int e = blockIdx.x*256+threadIdx.x;
  if (e<E) atomicAdd(&g_cnt[which][dst[e]], 1);
}

__global__ __launch_bounds__(1024) void k_scan(){
  int which = blockIdx.y;
  int* row_start = g_rs[which];
  const int* cnt = g_cnt[which];
  int* cur = g_cur[which];
  __shared__ int buf[1024];
  int tid = threadIdx.x;
  const int n = NN;
  int chunk = (n + 1023) >> 10;
  int start = tid*chunk; if (start>n) start=n;
  int end = start+chunk; if (end>n) end=n;
  int lsum=0;
  for (int i=start;i<end;++i) lsum += cnt[i];
  buf[tid]=lsum;
  __syncthreads();
  for (int off=1; off<1024; off<<=1){
    int t = (tid>=off)? buf[tid-off]:0;
    __syncthreads();
    buf[tid] += t;
    __syncthreads();
  }
  int run = buf[tid]-lsum;
  for (int i=start;i<end;++i){ row_start[i]=run; cur[i]=run; run += cnt[i]; }
  if (tid==1023) row_start[n]=run;
}

// scatter: CSR-ordered src + raw edge attrs (edge encoder folded into k_aggc coefficients)
__global__ void k_scatter(const int* __restrict__ eit, const int* __restrict__ eih,
                          const float* __restrict__ attrT, const float* __restrict__ attrH){
  int which = blockIdx.y;
  int e = blockIdx.x*256+threadIdx.x;
  if (which==0){
    if (e>=ET_N) return;
    int src = eit[e], dst = eit[ET_N+e];
    int p = atomicAdd(&g_cur[0][dst],1);
    g_srcc[0][p]=src;
    g_ta[p]=attrT[e];
  } else {
    if (e>=EH_N) return;
    int src = eih[e], dst = eih[EH_N+e];
    int p = atomicAdd(&g_cur[1][dst],1);
    g_srcc[1][p]=src;
    g_ha[p]=make_float4(attrH[e*3+0],attrH[e*3+1],attrH[e*3+2],0.f);
  }
}

// ---------- bf16 MFMA GEMM ----------
// grid (cdiv(NN,64), 6): y = conv*3 + kind, kind 0=Q, 1=KV(two matmuls), 2=S
// block 256 = 4 waves; wave w owns cols [w*32, w*32+32); 64x128 tile; K=128 staged once.
// LDS XOR swizzle: off ^= ((row&7)<<4) on 16B-granular offsets (G4).
struct BiasP { const float* b[8]; };

__global__ __launch_bounds__(256) void k_gemm_mfma(int l, BiasP bp){
  __shared__ unsigned short lA[64*DD];    // 16 KB
  __shared__ unsigned short lB[DD*DD];    // 32 KB
  int y = blockIdx.y;
  int conv = y/3, kind = y%3;             // 0 Q, 1 KV, 2 S
  int setbase = l*8 + conv*4;
  const unsigned short* Wm0 = &g_Wb[(size_t)(setbase + (kind==0?0:(kind==1?1:3)))*DD*DD];
  const unsigned short* Wm1 = &g_Wb[(size_t)(setbase+2)*DD*DD];   // V weights (kind==1 only)
  int tid = threadIdx.x;
  int m0 = blockIdx.x*64;

#pragma unroll
  for (int p=0;p<4;++p){
    int c = tid + p*256;
    int row = c >> 4, col16 = c & 15;
    int grow = m0 + row;
    uint4 v = make_uint4(0,0,0,0);
    if (grow < NN) v = *reinterpret_cast<const uint4*>(&g_hb[(size_t)grow*DD + col16*8]);
    int off = (row*256 + col16*16) ^ ((row&7)<<4);
    *reinterpret_cast<uint4*>((char*)lA + off) = v;
  }
#pragma unroll
  for (int p=0;p<8;++p){
    int c = tid + p*256;
    int row = c >> 4, col16 = c & 15;
    uint4 v = *reinterpret_cast<const uint4*>(&Wm0[(size_t)row*DD + col16*8]);
    int off = (row*256 + col16*16) ^ ((row&7)<<4);
    *reinterpret_cast<uint4*>((char*)lB + off) = v;
  }
  __syncthreads();

  int wave = tid >> 6, lane = tid & 63;
  int lrow = lane & 15, kg = lane >> 4;
  int n0w = wave*32;

  short8 a[4][4];
#pragma unroll
  for (int kk=0;kk<4;++kk){
    int kbyte = kk*64 + kg*16;
#pragma unroll
    for (int mi=0;mi<4;++mi){
      int row = mi*16 + lrow;
      int off = (row*256 + kbyte) ^ ((row&7)<<4);
      a[kk][mi] = *reinterpret_cast<const short8*>((char*)lA + off);
    }
  }

  f32x4 acc[4][2];
#pragma unroll
  for (int mi=0;mi<4;++mi)
#pragma unroll
    for (int ni=0;ni<2;++ni) acc[mi][ni] = (f32x4){0.f,0.f,0.f,0.f};

#pragma unroll
  for (int kk=0;kk<4;++kk){
    int kbyte = kk*64 + kg*16;
    short8 b[2];
#pragma unroll
    for (int ni=0;ni<2;++ni){
      int n = n0w + ni*16 + lrow;
      int off = (n*256 + kbyte) ^ ((n&7)<<4);
      b[ni] = *reinterpret_cast<const short8*>((char*)lB + off);
    }
#pragma unroll
    for (int mi=0;mi<4;++mi)
#pragma unroll
      for (int ni=0;ni<2;++ni)
        acc[mi][ni] = __builtin_amdgcn_mfma_f32_16x16x32_bf16(a[kk][mi], b[ni], acc[mi][ni], 0,0,0);
  }

  f32x4 acc2[4][2];
  if (kind==1){
    __syncthreads();
#pragma unroll
    for (int p=0;p<8;++p){
      int c = tid + p*256;
      int row = c >> 4, col16 = c & 15;
      uint4 v = *reinterpret_cast<const uint4*>(&Wm1[(size_t)row*DD + col16*8]);
      int off = (row*256 + col16*16) ^ ((row&7)<<4);
      *reinterpret_cast<uint4*>((char*)lB + off) = v;
    }
    __syncthreads();
#pragma unroll
    for (int mi=0;mi<4;++mi)
#pragma unroll
      for (int ni=0;ni<2;++ni) acc2[mi][ni] = (f32x4){0.f,0.f,0.f,0.f};
#pragma unroll
    for (int kk=0;kk<4;++kk){
      int kbyte = kk*64 + kg*16;
      short8 b[2];
#pragma unroll
      for (int ni=0;ni<2;++ni){
        int n = n0w + ni*16 + lrow;
        int off = (n*256 + kbyte) ^ ((n&7)<<4);
        b[ni] = *reinterpret_cast<const short8*>((char*)lB + off);
      }
#pragma unroll
      for (int mi=0;mi<4;++mi)
#pragma unroll
        for (int ni=0;ni<2;++ni)
          acc2[mi][ni] = __builtin_amdgcn_mfma_f32_16x16x32_bf16(a[kk][mi], b[ni], acc2[mi][ni], 0,0,0);
    }
  }

  // epilogue: C/D layout col=lane&15, row=(lane>>4)*4+reg  [m89]
  const float* bias0 = bp.b[conv*4 + (kind==0?0:(kind==1?1:3))];
  const float* bias1 = bp.b[conv*4 + 2];
#pragma unroll
  for (int ni=0;ni<2;++ni){
    int col = n0w + ni*16 + lrow;
    float bs0 = bias0[col];
    float bs1 = (kind==1) ? bias1[col] : 0.f;
#pragma unroll
    for (int mi=0;mi<4;++mi){
#pragma unroll
      for (int r=0;r<4;++r){
        int row = m0 + mi*16 + kg*4 + r;
        if (row >= NN) continue;
        size_t o = (size_t)row*DD + col;
        if (kind==1){
          ushort2 kv;
          kv.x = f2bf(acc[mi][ni][r]  + bs0);
          kv.y = f2bf(acc2[mi][ni][r] + bs1);
          g_KV[conv][o] = kv;
        } else {
          float* op = (kind==0) ? g_Q[conv] : g_S[conv];
          op[o] = acc[mi][ni][r] + bs0;
        }
      }
    }
  }
}

// ---------- wave(64)-wide helpers ----------
__device__ inline float waveRed(float v){
  v += __shfl_xor(v,32); v += __shfl_xor(v,16); v += __shfl_xor(v,8);
  v += __shfl_xor(v,4);  v += __shfl_xor(v,2);  v += __shfl_xor(v,1);
  return v;
}

// ---------- fused aggregation + combine ----------
// grid (NN); block 256: threads 0-127 = temporal conv channels, 128-255 = host conv.
// After both online-softmax loops: LDS exchange, 128-ch LayerNorm, silu, residual into g_h/g_hb.
__global__ __launch_bounds__(256) void k_aggc(
    const float* __restrict__ WeT, const float* __restrict__ WeH,
    const float* __restrict__ Wt,  const float* __restrict__ bt4,
    const float* __restrict__ Wh,  const float* __restrict__ bh4,
    const float* __restrict__ ng,  const float* __restrict__ nb){
  int tid = threadIdx.x;
  int conv = tid >> 7;
  int d = tid & 127;
  int i = blockIdx.x;

  // fold edge-encoder @ lin_edge into per-channel coefficients
  float c0=0.f,c1=0.f,c2=0.f,c3=0.f;
  if (conv==0){
#pragma unroll
    for (int j=0;j<4;++j){ float w=WeT[j*DD+d]; c1 += Wt[j]*w; c0 += bt4[j]*w; }
  } else {
#pragma unroll
    for (int j=0;j<4;++j){
      float w=WeH[j*DD+d];
      c0 += Wh[j]*w; c1 += Wh[4+j]*w; c2 += Wh[8+j]*w; c3 += bh4[j]*w;
    }
  }

  float qd = g_Q[conv][(size_t)i*DD+d];
  const int*     srcc = g_srcc[conv];
  const ushort2* KV   = g_KV[conv];
  int beg=g_rs[conv][i], end=g_rs[conv][i+1];
  float m=-INFINITY, den=0.f, acc=0.f;
  if (beg<end){
    int s = srcc[beg];
    float4 at = make_float4(0.f,0.f,0.f,0.f);
    if (conv==0) at.x = g_ta[beg]; else at = g_ha[beg];
    ushort2 kv = KV[(size_t)s*DD+d];
    for (int idx=beg; idx<end; ++idx){
      ushort2 kv_n = kv; float4 at_n = at;
      if (idx+1<end){
        int s_n = srcc[idx+1];
        if (conv==0) at_n.x = g_ta[idx+1]; else at_n = g_ha[idx+1];
        kv_n = KV[(size_t)s_n*DD+d];
      }
      float eev = (conv==0) ? fmaf(at.x, c1, c0)
                            : (at.x*c0 + at.y*c1 + at.z*c2 + c3);
      float kf = bf2f(kv.x), vf = bf2f(kv.y);
      float p = qd*(kf+eev);
      p += __shfl_xor(p,16); p += __shfl_xor(p,8); p += __shfl_xor(p,4);
      p += __shfl_xor(p,2);  p += __shfl_xor(p,1);
      float a = p*0.17677669529663687f;   // 1/sqrt(32)
      float nm = fmaxf(m,a);
      float sc = __expf(m-nm);            // exp(-inf)=0 on first edge
      float ea = __expf(a-nm);
      den = den*sc + ea;
      acc = acc*sc + ea*(vf+eev);
      m = nm;
      kv = kv_n; at = at_n;
    }
  }
  float r = acc/(den+1e-16f) + g_S[conv][(size_t)i*DD+d];

  // ---- fused combine: h += silu(LN(r_t + r_h)) ----
  __shared__ float xch[DD];
  __shared__ float red[4];
  if (conv==1) xch[d] = r;
  __syncthreads();
  float v = (conv==0) ? (r + xch[d]) : 0.f;
  float s1 = waveRed(v);
  if ((tid&63)==0) red[tid>>6] = s1;
  __syncthreads();
  float mean = (red[0]+red[1])*(1.f/128.f);
  float dv = v - mean;
  float q2 = waveRed(dv*dv);
  __syncthreads();
  if ((tid&63)==0) red[tid>>6] = q2;
  __syncthreads();
  if (conv==0){
    float inv = 1.f/sqrtf((red[0]+red[1])*(1.f/128.f)+1e-5f);
    float c = dv*inv*ng[d] + nb[d];
    size_t o = (size_t)i*DD+d;
    float h = g_h[o] + c/(1.f+__expf(-c));
    g_h[o]=h; g_hb[o]=f2bf(h);
  }
}

// in-place final layernorm on g_h
__global__ __launch_bounds__(256) void k_finalln(const float* __restrict__ g, const float* __restrict__ b){
  int lane = threadIdx.x & 63;
  int node = blockIdx.x*4 + (threadIdx.x>>6);
  if (node>=NN) return;
  size_t i0 = (size_t)node*DD + lane, i1 = i0+64;
  float v0 = g_h[i0], v1 = g_h[i1];
  float s = waveRed(v0+v1);
  float mean = s*(1.f/128.f);
  float d0=v0-mean, d1=v1-mean;
  float q = waveRed(d0*d0+d1*d1);
  float inv = 1.f/sqrtf(q*(1.f/128.f)+1e-5f);
  g_h[i0]=d0*inv*g[lane]+b[lane];
  g_h[i1]=d1*inv*g[lane+64]+b[lane+64];
}

// mlp head: out3 = LN(silu(g_h@W1+b1)) @ W2 + b2 ; 8 nodes per block
__global__ __launch_bounds__(128) void k_head(
      const float* __restrict__ W1, const float* __restrict__ b1,
      const float* __restrict__ g, const float* __restrict__ bt,
      const float* __restrict__ W2, const float* __restrict__ b2,
      float* __restrict__ out){
  int d = threadIdx.x;
  int wv = d >> 6;
  int i0 = blockIdx.x*8;
  const int n = NN;
  __shared__ float rows[8][DD];
  __shared__ float comb[2];
#pragma unroll
  for (int t=0;t<8;++t){
    int node = i0+t;
    rows[t][d] = (node<n)? g_h[(size_t)node*DD+d] : 0.f;
  }
  __syncthreads();
  float z[8];
  float b1d = b1[d];
#pragma unroll
  for (int t=0;t<8;++t) z[t]=b1d;
  for (int k=0;k<DD;++k){
    float w = W1[k*DD+d];
#pragma unroll
    for (int t=0;t<8;++t) z[t] += rows[t][k]*w;
  }
#pragma unroll
  for (int t=0;t<8;++t){ float v=z[t]; z[t] = v/(1.f+expf(-v)); }
  float gd=g[d], btd=bt[d];
  float w2a=W2[d*3+0], w2b=W2[d*3+1], w2c=W2[d*3+2];
  float b2a=b2[0], b2b=b2[1], b2c=b2[2];
  for (int t=0;t<8;++t){
    int node=i0+t;
    float zz=z[t];
    float s = waveRed(zz);
    if ((d&63)==0) comb[wv]=s;
    __syncthreads();
    float mean=(comb[0]+comb[1])*(1.f/128.f);
    __syncthreads();
    float dv=zz-mean;
    float q2 = waveRed(dv*dv);
    if ((d&63)==0) comb[wv]=q2;
    __syncthreads();
    float inv = 1.f/sqrtf((comb[0]+comb[1])*(1.f/128.f)+1e-5f);
    __syncthreads();
    float zn = dv*inv*gd+btd;
    float p0 = waveRed(zn*w2a);
    if ((d&63)==0) comb[wv]=p0;
    __syncthreads();
    float o0 = comb[0]+comb[1]+b2a;
    __syncthreads();
    float p1 = waveRed(zn*w2b);
    if ((d&63)==0) comb[wv]=p1;
    __syncthreads();
    float o1 = comb[0]+comb[1]+b2b;
    __syncthreads();
    float p2 = waveRed(zn*w2c);
    if ((d&63)==0) comb[wv]=p2;
    __syncthreads();
    float o2 = comb[0]+comb[1]+b2c;
    __syncthreads();
    if (d==0 && node<n){
      out[(size_t)node*3+0]=o0; out[(size_t)node*3+1]=o1; out[(size_t)node*3+2]=o2;
    }
  }
}

extern "C" void kernel_launch(void* const* d_in, const int* in_sizes, int n_in,
                              void* d_out, int out_size, void* d_ws, size_t ws_size,
                              hipStream_t stream){
  (void)in_sizes; (void)n_in; (void)out_size; (void)d_ws; (void)ws_size;
  const float* x    = (const float*)d_in[0];
  const int*   eit  = (const int*)d_in[1];
  const int*   eih  = (const int*)d_in[2];
  const float* eat  = (const float*)d_in[3];
  const float* eah  = (const float*)d_in[4];
  const float* W_te = (const float*)d_in[5];
  const float* b_te = (const float*)d_in[6];
  const float* W_he = (const float*)d_in[7];
  const float* b_he = (const float*)d_in[8];
  const float *Wq_t=(const float*)d_in[9],  *bq_t=(const float*)d_in[10];
  const float *Wk_t=(const float*)d_in[11], *bk_t=(const float*)d_in[12];
  const float *Wv_t=(const float*)d_in[13], *bv_t=(const float*)d_in[14];
  const float *We_t=(const float*)d_in[15];
  const float *Ws_t=(const float*)d_in[16], *bs_t=(const float*)d_in[17];
  const float *Wq_h=(const float*)d_in[18], *bq_h=(const float*)d_in[19];
  const float *Wk_h=(const float*)d_in[20], *bk_h=(const float*)d_in[21];
  const float *Wv_h=(const float*)d_in[22], *bv_h=(const float*)d_in[23];
  const float *We_h=(const float*)d_in[24];
  const float *Ws_h=(const float*)d_in[25], *bs_h=(const float*)d_in[26];
  const float *norm_g=(const float*)d_in[27], *norm_b=(const float*)d_in[28];
  const float *fg=(const float*)d_in[29], *fb=(const float*)d_in[30];
  const float *dW1=(const float*)d_in[31], *db1=(const float*)d_in[32];
  const float *dg=(const float*)d_in[33],  *dbt=(const float*)d_in[34];
  const float *dW2=(const float*)d_in[35], *db2=(const float*)d_in[36];
  const float *sW1=(const float*)d_in[37], *sb1=(const float*)d_in[38];
  const float *sg=(const float*)d_in[39],  *sbt=(const float*)d_in[40];
  const float *sW2=(const float*)d_in[41], *sb2=(const float*)d_in[42];
  float* outp = (float*)d_out;

  k_copy_h<<<cdiv(NN*DD/4,256),256,0,stream>>>(x);

  WPtrs wp;
  for (int l=0;l<NL;++l){
    wp.W[l*8+0]=Wq_t+(size_t)l*DD*DD; wp.W[l*8+1]=Wk_t+(size_t)l*DD*DD;
    wp.W[l*8+2]=Wv_t+(size_t)l*DD*DD; wp.W[l*8+3]=Ws_t+(size_t)l*DD*DD;
    wp.W[l*8+4]=Wq_h+(size_t)l*DD*DD; wp.W[l*8+5]=Wk_h+(size_t)l*DD*DD;
    wp.W[l*8+6]=Wv_h+(size_t)l*DD*DD; wp.W[l*8+7]=Ws_h+(size_t)l*DD*DD;
  }
  k_cvtw<<<dim3(64,24),256,0,stream>>>(wp);

  k_zero_cnt<<<dim3(cdiv(NN,256),2),256,0,stream>>>();
  k_hist<<<dim3(cdiv(ET_N,256),2),256,0,stream>>>(eit+ET_N, eih+EH_N);
  k_scan<<<dim3(1,2),1024,0,stream>>>();
  k_scatter<<<dim3(cdiv(ET_N,256),2),256,0,stream>>>(eit, eih, eat, eah);

  for (int l=0;l<NL;++l){
    BiasP bp;
    bp.b[0]=bq_t+(size_t)l*DD; bp.b[1]=bk_t+(size_t)l*DD;
    bp.b[2]=bv_t+(size_t)l*DD; bp.b[3]=bs_t+(size_t)l*DD;
    bp.b[4]=bq_h+(size_t)l*DD; bp.b[5]=bk_h+(size_t)l*DD;
    bp.b[6]=bv_h+(size_t)l*DD; bp.b[7]=bs_h+(size_t)l*DD;
    k_gemm_mfma<<<dim3(cdiv(NN,64),6),256,0,stream>>>(l, bp);
    k_aggc<<<NN,256,0,stream>>>(We_t+(size_t)l*4*DD, We_h+(size_t)l*4*DD,
                                W_te, b_te, W_he, b_he,
                                norm_g+(size_t)l*DD, norm_b+(size_t)l*DD);
  }
  k_finalln<<<cdiv(NN,4),256,0,stream>>>(fg, fb);
  k_head<<<cdiv(NN,8),128,0,stream>>>(dW1, db1, dg, dbt, dW2, db2, outp);
  k_head<<<cdiv(NN,8),128,0,stream>>>(sW1, sb1, sg, sbt, sW2, sb2, outp+(size_t)NN*3);
}

// Round 7
// 1318.244 us; speedup vs baseline: 1.2609x; 1.2609x over previous
//
#include <hip/hip_runtime.h>
#include <math.h>

#define NN 50000
#define DD 128
#define ET_N 640000
#define EH_N 320000
#define NL 3

static inline int cdiv(int a, int b){ return (a+b-1)/b; }

typedef __attribute__((ext_vector_type(8))) short short8;
typedef __attribute__((ext_vector_type(4))) float f32x4;

// ---------------- compiled-in device scratch (no d_ws dependency) ----------------
__device__ float   g_h [(size_t)NN*DD];
__device__ unsigned short g_hb[(size_t)NN*DD];        // bf16 copy of h (GEMM A input)
__device__ unsigned short g_Wb[(size_t)NL*8*DD*DD];   // bf16, TRANSPOSED [n][k]; l*8 + {tQ,tK,tV,tS,hQ,hK,hV,hS}
__device__ float   g_Q [2][(size_t)NN*DD];
__device__ float   g_S [2][(size_t)NN*DD];
__device__ ushort2 g_KV[2][(size_t)NN*DD];   // .x = K bf16 bits, .y = V bf16 bits
__device__ float   g_to[(size_t)NN*DD];      // temporal conv output
__device__ float   g_ho[(size_t)NN*DD];      // host conv output
__device__ int     g_cnt[2][NN];
__device__ int     g_cur[2][NN];
__device__ int     g_rs [2][NN+1];
__device__ int     g_srcc[2][ET_N];          // CSR-ordered src (conv1 uses first EH_N)
__device__ float   g_ta[ET_N];               // CSR-ordered temporal attr (scalar)
__device__ float4  g_ha[EH_N];               // CSR-ordered host attr (3 used)

__device__ inline unsigned short f2bf(float f){
  unsigned u = __float_as_uint(f);
  unsigned r = (u + 0x7fffu + ((u>>16)&1u)) >> 16;   // RNE
  return (unsigned short)r;
}
__device__ inline float bf2f(unsigned short s){
  return __uint_as_float(((unsigned)s)<<16);
}

// ---------------- tiny helpers ----------------
__global__ void k_copy_h(const float* __restrict__ x){
  int i = blockIdx.x*256 + threadIdx.x;           // float4 index
  if (i < NN*DD/4){
    float4 v = reinterpret_cast<const float4*>(x)[i];
    reinterpret_cast<float4*>(g_h)[i] = v;
    ushort4 b; b.x=f2bf(v.x); b.y=f2bf(v.y); b.z=f2bf(v.z); b.w=f2bf(v.w);
    reinterpret_cast<ushort4*>(g_hb)[i] = b;
  }
}

__global__ void k_zero_cnt(){
  int i = blockIdx.x*256 + threadIdx.x;
  if (i < NN) g_cnt[blockIdx.y][i] = 0;
}

// convert + transpose conv weights to bf16 [n][k]
struct WPtrs { const float* W[24]; };
__global__ __launch_bounds__(256) void k_cvtw(WPtrs wp){
  int mat = blockIdx.y;
  const float* W = wp.W[mat];
  int e = blockIdx.x*256 + threadIdx.x;
  int n = e >> 7, k = e & 127;
  g_Wb[(size_t)mat*DD*DD + e] = f2bf(W[k*DD+n]);
}

// ---------- CSR build (by destination) ----------
__global__ void k_hist(const int* __restrict__ dstT, const int* __restrict__ dstH){
  int which = blockIdx.y;
  int E = which ? EH_N : ET_N;
  const int* dst = which ? dstH : dstT;
  int e = blockIdx.x*256+threadIdx.x;
  if (e<E) atomicAdd(&g_cnt[which][dst[e]], 1);
}

__global__ __launch_bounds__(1024) void k_scan(){
  int which = blockIdx.y;
  int* row_start = g_rs[which];
  const int* cnt = g_cnt[which];
  int* cur = g_cur[which];
  __shared__ int buf[1024];
  int tid = threadIdx.x;
  const int n = NN;
  int chunk = (n + 1023) >> 10;
  int start = tid*chunk; if (start>n) start=n;
  int end = start+chunk; if (end>n) end=n;
  int lsum=0;
  for (int i=start;i<end;++i) lsum += cnt[i];
  buf[tid]=lsum;
  __syncthreads();
  for (int off=1; off<1024; off<<=1){
    int t = (tid>=off)? buf[tid-off]:0;
    __syncthreads();
    buf[tid] += t;
    __syncthreads();
  }
  int run = buf[tid]-lsum;
  for (int i=start;i<end;++i){ row_start[i]=run; cur[i]=run; run += cnt[i]; }
  if (tid==1023) row_start[n]=run;
}

// scatter: CSR-ordered src + raw edge attrs
__global__ void k_scatter(const int* __restrict__ eit, const int* __restrict__ eih,
                          const float* __restrict__ attrT, const float* __restrict__ attrH){
  int which = blockIdx.y;
  int e = blockIdx.x*256+threadIdx.x;
  if (which==0){
    if (e>=ET_N) return;
    int src = eit[e], dst = eit[ET_N+e];
    int p = atomicAdd(&g_cur[0][dst],1);
    g_srcc[0][p]=src;
    g_ta[p]=attrT[e];
  } else {
    if (e>=EH_N) return;
    int src = eih[e], dst = eih[EH_N+e];
    int p = atomicAdd(&g_cur[1][dst],1);
    g_srcc[1][p]=src;
    g_ha[p]=make_float4(attrH[e*3+0],attrH[e*3+1],attrH[e*3+2],0.f);
  }
}

// ---------- bf16 MFMA GEMM: one block computes Q,K,V,S for its 64-row tile ----------
// grid (cdiv(NN,64), 2): y = conv. A staged once; 4 B-phases. LDS XOR swizzle (G4).
struct BiasP { const float* b[8]; };

__global__ __launch_bounds__(256) void k_gemm_mfma(int l, BiasP bp){
  __shared__ unsigned short lA[64*DD];    // 16 KB
  __shared__ unsigned short lB[DD*DD];    // 32 KB
  int conv = blockIdx.y;
  int setbase = l*8 + conv*4;             // +0 Q, +1 K, +2 V, +3 S
  int tid = threadIdx.x;
  int m0 = blockIdx.x*64;

  // stage A once
#pragma unroll
  for (int p=0;p<4;++p){
    int c = tid + p*256;
    int row = c >> 4, col16 = c & 15;
    int grow = m0 + row;
    uint4 v = make_uint4(0,0,0,0);
    if (grow < NN) v = *reinterpret_cast<const uint4*>(&g_hb[(size_t)grow*DD + col16*8]);
    int off = (row*256 + col16*16) ^ ((row&7)<<4);
    *reinterpret_cast<uint4*>((char*)lA + off) = v;
  }

  int wave = tid >> 6, lane = tid & 63;
  int lrow = lane & 15, kg = lane >> 4;
  int n0w = wave*32;

  auto stageB = [&](const unsigned short* Wm){
#pragma unroll
    for (int p=0;p<8;++p){
      int c = tid + p*256;
      int row = c >> 4, col16 = c & 15;
      uint4 v = *reinterpret_cast<const uint4*>(&Wm[(size_t)row*DD + col16*8]);
      int off = (row*256 + col16*16) ^ ((row&7)<<4);
      *reinterpret_cast<uint4*>((char*)lB + off) = v;
    }
  };

  stageB(&g_Wb[(size_t)(setbase+0)*DD*DD]);   // Q weights
  __syncthreads();

  // A fragments into registers (lA never overwritten)
  short8 a[4][4];
#pragma unroll
  for (int kk=0;kk<4;++kk){
    int kbyte = kk*64 + kg*16;
#pragma unroll
    for (int mi=0;mi<4;++mi){
      int row = mi*16 + lrow;
      int off = (row*256 + kbyte) ^ ((row&7)<<4);
      a[kk][mi] = *reinterpret_cast<const short8*>((char*)lA + off);
    }
  }

  auto computeC = [&](f32x4 (&acc)[4][2]){
#pragma unroll
    for (int mi=0;mi<4;++mi)
#pragma unroll
      for (int ni=0;ni<2;++ni) acc[mi][ni] = (f32x4){0.f,0.f,0.f,0.f};
#pragma unroll
    for (int kk=0;kk<4;++kk){
      int kbyte = kk*64 + kg*16;
      short8 b[2];
#pragma unroll
      for (int ni=0;ni<2;++ni){
        int n = n0w + ni*16 + lrow;
        int off = (n*256 + kbyte) ^ ((n&7)<<4);
        b[ni] = *reinterpret_cast<const short8*>((char*)lB + off);
      }
#pragma unroll
      for (int mi=0;mi<4;++mi)
#pragma unroll
        for (int ni=0;ni<2;++ni)
          acc[mi][ni] = __builtin_amdgcn_mfma_f32_16x16x32_bf16(a[kk][mi], b[ni], acc[mi][ni], 0,0,0);
    }
  };

  f32x4 acc[4][2], accK[4][2];

  // ---- Q ----
  computeC(acc);
  {
    const float* bias = bp.b[conv*4+0];
    float* op = g_Q[conv];
#pragma unroll
    for (int ni=0;ni<2;++ni){
      int col = n0w + ni*16 + lrow;
      float bs = bias[col];
#pragma unroll
      for (int mi=0;mi<4;++mi)
#pragma unroll
        for (int r=0;r<4;++r){
          int row = m0 + mi*16 + kg*4 + r;
          if (row < NN) op[(size_t)row*DD + col] = acc[mi][ni][r] + bs;
        }
    }
  }
  __syncthreads();
  // ---- K (keep in regs) ----
  stageB(&g_Wb[(size_t)(setbase+1)*DD*DD]);
  __syncthreads();
  computeC(accK);
  __syncthreads();
  // ---- V, then pack KV ----
  stageB(&g_Wb[(size_t)(setbase+2)*DD*DD]);
  __syncthreads();
  computeC(acc);
  {
    const float* bK = bp.b[conv*4+1];
    const float* bV = bp.b[conv*4+2];
#pragma unroll
    for (int ni=0;ni<2;++ni){
      int col = n0w + ni*16 + lrow;
      float bk = bK[col], bv = bV[col];
#pragma unroll
      for (int mi=0;mi<4;++mi)
#pragma unroll
        for (int r=0;r<4;++r){
          int row = m0 + mi*16 + kg*4 + r;
          if (row < NN){
            ushort2 kv;
            kv.x = f2bf(accK[mi][ni][r] + bk);
            kv.y = f2bf(acc [mi][ni][r] + bv);
            g_KV[conv][(size_t)row*DD + col] = kv;
          }
        }
    }
  }
  __syncthreads();
  // ---- S ----
  stageB(&g_Wb[(size_t)(setbase+3)*DD*DD]);
  __syncthreads();
  computeC(acc);
  {
    const float* bias = bp.b[conv*4+3];
    float* op = g_S[conv];
#pragma unroll
    for (int ni=0;ni<2;++ni){
      int col = n0w + ni*16 + lrow;
      float bs = bias[col];
#pragma unroll
      for (int mi=0;mi<4;++mi)
#pragma unroll
        for (int r=0;r<4;++r){
          int row = m0 + mi*16 + kg*4 + r;
          if (row < NN) op[(size_t)row*DD + col] = acc[mi][ni][r] + bs;
        }
    }
  }
}

// ---------- wave helpers ----------
__device__ inline float waveRed(float v){
  v += __shfl_xor(v,32); v += __shfl_xor(v,16); v += __shfl_xor(v,8);
  v += __shfl_xor(v,4);  v += __shfl_xor(v,2);  v += __shfl_xor(v,1);
  return v;
}
__device__ inline float headRed(float v){   // sum over 32-lane head group
  v += __shfl_xor(v,16); v += __shfl_xor(v,8); v += __shfl_xor(v,4);
  v += __shfl_xor(v,2);  v += __shfl_xor(v,1);
  return v;
}

// ---------- per-dst-node attention aggregation ----------
// grid (NN,2); 128 threads (one per channel). Folded edge-embedding + dual-chain ILP.
__global__ __launch_bounds__(128) void k_agg(
    const float* __restrict__ WeT, const float* __restrict__ WeH,
    const float* __restrict__ Wt,  const float* __restrict__ bt4,
    const float* __restrict__ Wh,  const float* __restrict__ bh4){
  int conv = blockIdx.y;
  int i = blockIdx.x;
  int d = threadIdx.x;

  // per-channel edge-encoder coefficients (validated in r6)
  float c0=0.f,c1=0.f,c2=0.f,c3=0.f;
  if (conv==0){
#pragma unroll
    for (int j=0;j<4;++j){ float w=WeT[j*DD+d]; c1 += Wt[j]*w; c0 += bt4[j]*w; }
  } else {
#pragma unroll
    for (int j=0;j<4;++j){
      float w=WeH[j*DD+d];
      c0 += Wh[j]*w; c1 += Wh[4+j]*w; c2 += Wh[8+j]*w; c3 += bh4[j]*w;
    }
  }

  float qd = g_Q[conv][(size_t)i*DD+d];
  // per-(node,head) scalars: q.ee pieces
  float qe0,qe1,qe2=0.f,qe3=0.f;
  if (conv==0){
    qe0 = headRed(qd*c0);
    qe1 = headRed(qd*c1);
  } else {
    qe0 = headRed(qd*c0);
    qe1 = headRed(qd*c1);
    qe2 = headRed(qd*c2);
    qe3 = headRed(qd*c3);
  }

  const int*     srcc = g_srcc[conv];
  const ushort2* KV   = g_KV[conv];
  int beg=g_rs[conv][i], end=g_rs[conv][i+1];
  int cnt = end-beg;

  const float inv32 = 0.17677669529663687f;   // 1/sqrt(32)
  float mA=-INFINITY,dnA=0.f,acA=0.f,x0A=0.f,x1A=0.f,x2A=0.f;
  float mB=-INFINITY,dnB=0.f,acB=0.f,x0B=0.f,x1B=0.f,x2B=0.f;

  if (cnt>0){
    // preload first pair
    ushort2 kv0=make_ushort2(0,0), kv1=make_ushort2(0,0);
    float4 a0v=make_float4(0.f,0.f,0.f,0.f), a1v=a0v;
    bool h1;
    {
      int s0=srcc[beg];
      if (conv==0) a0v.x=g_ta[beg]; else a0v=g_ha[beg];
      kv0=KV[(size_t)s0*DD+d];
      h1 = (beg+1<end);
      if (h1){
        int s1=srcc[beg+1];
        if (conv==0) a1v.x=g_ta[beg+1]; else a1v=g_ha[beg+1];
        kv1=KV[(size_t)s1*DD+d];
      }
    }
    for (int t=beg; t<end; t+=2){
      ushort2 ckv0=kv0, ckv1=kv1; float4 ca0=a0v, ca1=a1v; bool ch1=h1;
      int tn=t+2;
      if (tn<end){
        int s0=srcc[tn];
        if (conv==0) a0v.x=g_ta[tn]; else a0v=g_ha[tn];
        kv0=KV[(size_t)s0*DD+d];
        h1 = (tn+1<end);
        if (h1){
          int s1=srcc[tn+1];
          if (conv==0) a1v.x=g_ta[tn+1]; else a1v=g_ha[tn+1];
          kv1=KV[(size_t)s1*DD+d];
        }
      }
      float p0 = qd*bf2f(ckv0.x);
      float p1 = ch1 ? qd*bf2f(ckv1.x) : 0.f;
#pragma unroll
      for (int mk=16; mk>=1; mk>>=1){ p0 += __shfl_xor(p0,mk); p1 += __shfl_xor(p1,mk); }
      float lg0, lg1;
      if (conv==0){
        lg0 = (p0 + qe0 + ca0.x*qe1)*inv32;
        lg1 = (p1 + qe0 + ca1.x*qe1)*inv32;
      } else {
        lg0 = (p0 + ca0.x*qe0 + ca0.y*qe1 + ca0.z*qe2 + qe3)*inv32;
        lg1 = (p1 + ca1.x*qe0 + ca1.y*qe1 + ca1.z*qe2 + qe3)*inv32;
      }
      {
        float nm=fmaxf(mA,lg0), sc=__expf(mA-nm), ea=__expf(lg0-nm);
        dnA=dnA*sc+ea; acA=acA*sc+ea*bf2f(ckv0.y);
        x0A=x0A*sc+ea*ca0.x;
        if (conv==1){ x1A=x1A*sc+ea*ca0.y; x2A=x2A*sc+ea*ca0.z; }
        mA=nm;
      }
      if (ch1){
        float nm=fmaxf(mB,lg1), sc=__expf(mB-nm), ea=__expf(lg1-nm);
        dnB=dnB*sc+ea; acB=acB*sc+ea*bf2f(ckv1.y);
        x0B=x0B*sc+ea*ca1.x;
        if (conv==1){ x1B=x1B*sc+ea*ca1.y; x2B=x2B*sc+ea*ca1.z; }
        mB=nm;
      }
    }
  }

  float r;
  if (cnt==0){
    r = 0.f;
  } else {
    float mm = fmaxf(mA,mB);
    float eA = __expf(mA-mm), eB = __expf(mB-mm);
    float den = dnA*eA + dnB*eB;
    float ac  = acA*eA + acB*eB;
    float x0  = x0A*eA + x0B*eB;
    float id = 1.f/den;                 // den >= 1 when edges exist
    if (conv==0){
      r = ac*id + c0 + c1*(x0*id);
    } else {
      float x1 = x1A*eA + x1B*eB;
      float x2 = x2A*eA + x2B*eB;
      r = ac*id + c0*(x0*id) + c1*(x1*id) + c2*(x2*id) + c3;
    }
  }
  r += g_S[conv][(size_t)i*DD+d];
  float* o = conv ? g_ho : g_to;
  o[(size_t)i*DD+d] = r;
}

// g_h += silu(layernorm(g_to + g_ho)) ; one wave per node, 4 nodes per block
__global__ __launch_bounds__(256) void k_combine(const float* __restrict__ g, const float* __restrict__ bt){
  int lane = threadIdx.x & 63;
  int node = blockIdx.x*4 + (threadIdx.x>>6);
  if (node>=NN) return;
  size_t i0 = (size_t)node*DD + lane, i1 = i0+64;
  float v0 = g_to[i0] + g_ho[i0];
  float v1 = g_to[i1] + g_ho[i1];
  float s = waveRed(v0+v1);
  float mean = s*(1.f/128.f);
  float d0=v0-mean, d1=v1-mean;
  float q = waveRed(d0*d0+d1*d1);
  float inv = 1.f/sqrtf(q*(1.f/128.f)+1e-5f);
  float c0 = d0*inv*g[lane]+bt[lane];
  float c1 = d1*inv*g[lane+64]+bt[lane+64];
  float h0 = g_h[i0] + c0/(1.f+__expf(-c0));
  float h1 = g_h[i1] + c1/(1.f+__expf(-c1));
  g_h[i0] = h0; g_h[i1] = h1;
  g_hb[i0] = f2bf(h0); g_hb[i1] = f2bf(h1);
}

// in-place final layernorm on g_h
__global__ __launch_bounds__(256) void k_finalln(const float* __restrict__ g, const float* __restrict__ b){
  int lane = threadIdx.x & 63;
  int node = blockIdx.x*4 + (threadIdx.x>>6);
  if (node>=NN) return;
  size_t i0 = (size_t)node*DD + lane, i1 = i0+64;
  float v0 = g_h[i0], v1 = g_h[i1];
  float s = waveRed(v0+v1);
  float mean = s*(1.f/128.f);
  float d0=v0-mean, d1=v1-mean;
  float q = waveRed(d0*d0+d1*d1);
  float inv = 1.f/sqrtf(q*(1.f/128.f)+1e-5f);
  g_h[i0]=d0*inv*g[lane]+b[lane];
  g_h[i1]=d1*inv*g[lane+64]+b[lane+64];
}

// mlp head: out3 = LN(silu(g_h@W1+b1)) @ W2 + b2 ; 8 nodes per block
__global__ __launch_bounds__(128) void k_head(
      const float* __restrict__ W1, const float* __restrict__ b1,
      const float* __restrict__ g, const float* __restrict__ bt,
      const float* __restrict__ W2, const float* __restrict__ b2,
      float* __restrict__ out){
  int d = threadIdx.x;
  int wv = d >> 6;
  int i0 = blockIdx.x*8;
  const int n = NN;
  __shared__ float rows[8][DD];
  __shared__ float comb[2];
#pragma unroll
  for (int t=0;t<8;++t){
    int node = i0+t;
    rows[t][d] = (node<n)? g_h[(size_t)node*DD+d] : 0.f;
  }
  __syncthreads();
  float z[8];
  float b1d = b1[d];
#pragma unroll
  for (int t=0;t<8;++t) z[t]=b1d;
  for (int k=0;k<DD;++k){
    float w = W1[k*DD+d];
#pragma unroll
    for (int t=0;t<8;++t) z[t] += rows[t][k]*w;
  }
#pragma unroll
  for (int t=0;t<8;++t){ float v=z[t]; z[t] = v/(1.f+expf(-v)); }
  float gd=g[d], btd=bt[d];
  float w2a=W2[d*3+0], w2b=W2[d*3+1], w2c=W2[d*3+2];
  float b2a=b2[0], b2b=b2[1], b2c=b2[2];
  for (int t=0;t<8;++t){
    int node=i0+t;
    float zz=z[t];
    float s = waveRed(zz);
    if ((d&63)==0) comb[wv]=s;
    __syncthreads();
    float mean=(comb[0]+comb[1])*(1.f/128.f);
    __syncthreads();
    float dv=zz-mean;
    float q2 = waveRed(dv*dv);
    if ((d&63)==0) comb[wv]=q2;
    __syncthreads();
    float inv = 1.f/sqrtf((comb[0]+comb[1])*(1.f/128.f)+1e-5f);
    __syncthreads();
    float zn = dv*inv*gd+btd;
    float p0 = waveRed(zn*w2a);
    if ((d&63)==0) comb[wv]=p0;
    __syncthreads();
    float o0 = comb[0]+comb[1]+b2a;
    __syncthreads();
    float p1 = waveRed(zn*w2b);
    if ((d&63)==0) comb[wv]=p1;
    __syncthreads();
    float o1 = comb[0]+comb[1]+b2b;
    __syncthreads();
    float p2 = waveRed(zn*w2c);
    if ((d&63)==0) comb[wv]=p2;
    __syncthreads();
    float o2 = comb[0]+comb[1]+b2c;
    __syncthreads();
    if (d==0 && node<n){
      out[(size_t)node*3+0]=o0; out[(size_t)node*3+1]=o1; out[(size_t)node*3+2]=o2;
    }
  }
}

extern "C" void kernel_launch(void* const* d_in, const int* in_sizes, int n_in,
                              void* d_out, int out_size, void* d_ws, size_t ws_size,
                              hipStream_t stream){
  (void)in_sizes; (void)n_in; (void)out_size; (void)d_ws; (void)ws_size;
  const float* x    = (const float*)d_in[0];
  const int*   eit  = (const int*)d_in[1];
  const int*   eih  = (const int*)d_in[2];
  const float* eat  = (const float*)d_in[3];
  const float* eah  = (const float*)d_in[4];
  const float* W_te = (const float*)d_in[5];
  const float* b_te = (const float*)d_in[6];
  const float* W_he = (const float*)d_in[7];
  const float* b_he = (const float*)d_in[8];
  const float *Wq_t=(const float*)d_in[9],  *bq_t=(const float*)d_in[10];
  const float *Wk_t=(const float*)d_in[11], *bk_t=(const float*)d_in[12];
  const float *Wv_t=(const float*)d_in[13], *bv_t=(const float*)d_in[14];
  const float *We_t=(const float*)d_in[15];
  const float *Ws_t=(const float*)d_in[16], *bs_t=(const float*)d_in[17];
  const float *Wq_h=(const float*)d_in[18], *bq_h=(const float*)d_in[19];
  const float *Wk_h=(const float*)d_in[20], *bk_h=(const float*)d_in[21];
  const float *Wv_h=(const float*)d_in[22], *bv_h=(const float*)d_in[23];
  const float *We_h=(const float*)d_in[24];
  const float *Ws_h=(const float*)d_in[25], *bs_h=(const float*)d_in[26];
  const float *norm_g=(const float*)d_in[27], *norm_b=(const float*)d_in[28];
  const float *fg=(const float*)d_in[29], *fb=(const float*)d_in[30];
  const float *dW1=(const float*)d_in[31], *db1=(const float*)d_in[32];
  const float *dg=(const float*)d_in[33],  *dbt=(const float*)d_in[34];
  const float *dW2=(const float*)d_in[35], *db2=(const float*)d_in[36];
  const float *sW1=(const float*)d_in[37], *sb1=(const float*)d_in[38];
  const float *sg=(const float*)d_in[39],  *sbt=(const float*)d_in[40];
  const float *sW2=(const float*)d_in[41], *sb2=(const float*)d_in[42];
  float* outp = (float*)d_out;

  k_copy_h<<<cdiv(NN*DD/4,256),256,0,stream>>>(x);

  WPtrs wp;
  for (int l=0;l<NL;++l){
    wp.W[l*8+0]=Wq_t+(size_t)l*DD*DD; wp.W[l*8+1]=Wk_t+(size_t)l*DD*DD;
    wp.W[l*8+2]=Wv_t+(size_t)l*DD*DD; wp.W[l*8+3]=Ws_t+(size_t)l*DD*DD;
    wp.W[l*8+4]=Wq_h+(size_t)l*DD*DD; wp.W[l*8+5]=Wk_h+(size_t)l*DD*DD;
    wp.W[l*8+6]=Wv_h+(size_t)l*DD*DD; wp.W[l*8+7]=Ws_h+(size_t)l*DD*DD;
  }
  k_cvtw<<<dim3(64,24),256,0,stream>>>(wp);

  k_zero_cnt<<<dim3(cdiv(NN,256),2),256,0,stream>>>();
  k_hist<<<dim3(cdiv(ET_N,256),2),256,0,stream>>>(eit+ET_N, eih+EH_N);
  k_scan<<<dim3(1,2),1024,0,stream>>>();
  k_scatter<<<dim3(cdiv(ET_N,256),2),256,0,stream>>>(eit, eih, eat, eah);

  for (int l=0;l<NL;++l){
    BiasP bp;
    bp.b[0]=bq_t+(size_t)l*DD; bp.b[1]=bk_t+(size_t)l*DD;
    bp.b[2]=bv_t+(size_t)l*DD; bp.b[3]=bs_t+(size_t)l*DD;
    bp.b[4]=bq_h+(size_t)l*DD; bp.b[5]=bk_h+(size_t)l*DD;
    bp.b[6]=bv_h+(size_t)l*DD; bp.b[7]=bs_h+(size_t)l*DD;
    k_gemm_mfma<<<dim3(cdiv(NN,64),2),256,0,stream>>>(l, bp);
    k_agg<<<dim3(NN,2),128,0,stream>>>(We_t+(size_t)l*4*DD, We_h+(size_t)l*4*DD,
                                       W_te, b_te, W_he, b_he);
    k_combine<<<cdiv(NN,4),256,0,stream>>>(norm_g+(size_t)l*DD, norm_b+(size_t)l*DD);
  }
  k_finalln<<<cdiv(NN,4),256,0,stream>>>(fg, fb);
  k_head<<<cdiv(NN,8),128,0,stream>>>(dW1, db1, dg, dbt, dW2, db2, outp);
  k_head<<<cdiv(NN,8),128,0,stream>>>(sW1, sb1, sg, sbt, sW2, sb2, outp+(size_t)NN*3);
}

// Round 8
// 1224.178 us; speedup vs baseline: 1.3578x; 1.0768x over previous
//
#include <hip/hip_runtime.h>
#include <math.h>

#define NN 50000
#define DD 128
#define ET_N 640000
#define EH_N 320000
#define NL 3

static inline int cdiv(int a, int b){ return (a+b-1)/b; }

typedef __attribute__((ext_vector_type(8))) short short8;
typedef __attribute__((ext_vector_type(4))) float f32x4;

// ---------------- compiled-in device scratch (no d_ws dependency) ----------------
__device__ float   g_h [(size_t)NN*DD];
__device__ unsigned short g_hb[(size_t)NN*DD];        // bf16 copy of h (GEMM A input)
__device__ unsigned short g_Wb[(size_t)NL*8*DD*DD];   // bf16, TRANSPOSED [n][k]; l*8 + {tQ,tK,tV,tS,hQ,hK,hV,hS}
__device__ float   g_Q [2][(size_t)NN*DD];
__device__ float   g_S [2][(size_t)NN*DD];
__device__ ushort2 g_KV[2][(size_t)NN*DD];   // .x = K bf16 bits, .y = V bf16 bits
__device__ float   g_to[(size_t)NN*DD];      // temporal conv output
__device__ float   g_ho[(size_t)NN*DD];      // host conv output
__device__ int     g_cnt[2][NN];
__device__ int     g_cur[2][NN];
__device__ int     g_rs [2][NN+1];
__device__ int     g_srcc[2][ET_N];          // CSR-ordered src (conv1 uses first EH_N)
__device__ float   g_ta[ET_N];               // CSR-ordered temporal attr (scalar)
__device__ float4  g_ha[EH_N];               // CSR-ordered host attr (3 used)

__device__ inline unsigned short f2bf(float f){
  unsigned u = __float_as_uint(f);
  unsigned r = (u + 0x7fffu + ((u>>16)&1u)) >> 16;   // RNE
  return (unsigned short)r;
}
__device__ inline float bf2f(unsigned short s){
  return __uint_as_float(((unsigned)s)<<16);
}
__device__ inline float bf_lo(unsigned u){ return __uint_as_float(u<<16); }
__device__ inline float bf_hi(unsigned u){ return __uint_as_float(u & 0xffff0000u); }

// ---------------- tiny helpers ----------------
__global__ void k_copy_h(const float* __restrict__ x){
  int i = blockIdx.x*256 + threadIdx.x;           // float4 index
  if (i < NN*DD/4){
    float4 v = reinterpret_cast<const float4*>(x)[i];
    reinterpret_cast<float4*>(g_h)[i] = v;
    ushort4 b; b.x=f2bf(v.x); b.y=f2bf(v.y); b.z=f2bf(v.z); b.w=f2bf(v.w);
    reinterpret_cast<ushort4*>(g_hb)[i] = b;
  }
}

__global__ void k_zero_cnt(){
  int i = blockIdx.x*256 + threadIdx.x;
  if (i < NN) g_cnt[blockIdx.y][i] = 0;
}

// convert + transpose conv weights to bf16 [n][k]
struct WPtrs { const float* W[24]; };
__global__ __launch_bounds__(256) void k_cvtw(WPtrs wp){
  int mat = blockIdx.y;
  const float* W = wp.W[mat];
  int e = blockIdx.x*256 + threadIdx.x;
  int n = e >> 7, k = e & 127;
  g_Wb[(size_t)mat*DD*DD + e] = f2bf(W[k*DD+n]);
}

// ---------- CSR build (by destination) ----------
__global__ void k_hist(const int* __restrict__ dstT, const int* __restrict__ dstH){
  int which = blockIdx.y;
  int E = which ? EH_N : ET_N;
  const int* dst = which ? dstH : dstT;
  int e = blockIdx.x*256+threadIdx.x;
  if (e<E) atomicAdd(&g_cnt[which][dst[e]], 1);
}

__global__ __launch_bounds__(1024) void k_scan(){
  int which = blockIdx.y;
  int* row_start = g_rs[which];
  const int* cnt = g_cnt[which];
  int* cur = g_cur[which];
  __shared__ int buf[1024];
  int tid = threadIdx.x;
  const int n = NN;
  int chunk = (n + 1023) >> 10;
  int start = tid*chunk; if (start>n) start=n;
  int end = start+chunk; if (end>n) end=n;
  int lsum=0;
  for (int i=start;i<end;++i) lsum += cnt[i];
  buf[tid]=lsum;
  __syncthreads();
  for (int off=1; off<1024; off<<=1){
    int t = (tid>=off)? buf[tid-off]:0;
    __syncthreads();
    buf[tid] += t;
    __syncthreads();
  }
  int run = buf[tid]-lsum;
  for (int i=start;i<end;++i){ row_start[i]=run; cur[i]=run; run += cnt[i]; }
  if (tid==1023) row_start[n]=run;
}

// scatter: CSR-ordered src + raw edge attrs
__global__ void k_scatter(const int* __restrict__ eit, const int* __restrict__ eih,
                          const float* __restrict__ attrT, const float* __restrict__ attrH){
  int which = blockIdx.y;
  int e = blockIdx.x*256+threadIdx.x;
  if (which==0){
    if (e>=ET_N) return;
    int src = eit[e], dst = eit[ET_N+e];
    int p = atomicAdd(&g_cur[0][dst],1);
    g_srcc[0][p]=src;
    g_ta[p]=attrT[e];
  } else {
    if (e>=EH_N) return;
    int src = eih[e], dst = eih[EH_N+e];
    int p = atomicAdd(&g_cur[1][dst],1);
    g_srcc[1][p]=src;
    g_ha[p]=make_float4(attrH[e*3+0],attrH[e*3+1],attrH[e*3+2],0.f);
  }
}

// ---------- bf16 MFMA GEMM: one block computes Q,K,V,S for its 64-row tile ----------
// grid (cdiv(NN,64), 2): y = conv. A staged once; 4 B-phases. LDS XOR swizzle (G4).
struct BiasP { const float* b[8]; };

__global__ __launch_bounds__(256) void k_gemm_mfma(int l, BiasP bp){
  __shared__ unsigned short lA[64*DD];    // 16 KB
  __shared__ unsigned short lB[DD*DD];    // 32 KB
  int conv = blockIdx.y;
  int setbase = l*8 + conv*4;             // +0 Q, +1 K, +2 V, +3 S
  int tid = threadIdx.x;
  int m0 = blockIdx.x*64;

  // stage A once
#pragma unroll
  for (int p=0;p<4;++p){
    int c = tid + p*256;
    int row = c >> 4, col16 = c & 15;
    int grow = m0 + row;
    uint4 v = make_uint4(0,0,0,0);
    if (grow < NN) v = *reinterpret_cast<const uint4*>(&g_hb[(size_t)grow*DD + col16*8]);
    int off = (row*256 + col16*16) ^ ((row&7)<<4);
    *reinterpret_cast<uint4*>((char*)lA + off) = v;
  }

  int wave = tid >> 6, lane = tid & 63;
  int lrow = lane & 15, kg = lane >> 4;
  int n0w = wave*32;

  auto stageB = [&](const unsigned short* Wm){
#pragma unroll
    for (int p=0;p<8;++p){
      int c = tid + p*256;
      int row = c >> 4, col16 = c & 15;
      uint4 v = *reinterpret_cast<const uint4*>(&Wm[(size_t)row*DD + col16*8]);
      int off = (row*256 + col16*16) ^ ((row&7)<<4);
      *reinterpret_cast<uint4*>((char*)lB + off) = v;
    }
  };

  stageB(&g_Wb[(size_t)(setbase+0)*DD*DD]);   // Q weights
  __syncthreads();

  // A fragments into registers (lA never overwritten)
  short8 a[4][4];
#pragma unroll
  for (int kk=0;kk<4;++kk){
    int kbyte = kk*64 + kg*16;
#pragma unroll
    for (int mi=0;mi<4;++mi){
      int row = mi*16 + lrow;
      int off = (row*256 + kbyte) ^ ((row&7)<<4);
      a[kk][mi] = *reinterpret_cast<const short8*>((char*)lA + off);
    }
  }

  auto computeC = [&](f32x4 (&acc)[4][2]){
#pragma unroll
    for (int mi=0;mi<4;++mi)
#pragma unroll
      for (int ni=0;ni<2;++ni) acc[mi][ni] = (f32x4){0.f,0.f,0.f,0.f};
#pragma unroll
    for (int kk=0;kk<4;++kk){
      int kbyte = kk*64 + kg*16;
      short8 b[2];
#pragma unroll
      for (int ni=0;ni<2;++ni){
        int n = n0w + ni*16 + lrow;
        int off = (n*256 + kbyte) ^ ((n&7)<<4);
        b[ni] = *reinterpret_cast<const short8*>((char*)lB + off);
      }
#pragma unroll
      for (int mi=0;mi<4;++mi)
#pragma unroll
        for (int ni=0;ni<2;++ni)
          acc[mi][ni] = __builtin_amdgcn_mfma_f32_16x16x32_bf16(a[kk][mi], b[ni], acc[mi][ni], 0,0,0);
    }
  };

  f32x4 acc[4][2], accK[4][2];

  // ---- Q ----
  computeC(acc);
  {
    const float* bias = bp.b[conv*4+0];
    float* op = g_Q[conv];
#pragma unroll
    for (int ni=0;ni<2;++ni){
      int col = n0w + ni*16 + lrow;
      float bs = bias[col];
#pragma unroll
      for (int mi=0;mi<4;++mi)
#pragma unroll
        for (int r=0;r<4;++r){
          int row = m0 + mi*16 + kg*4 + r;
          if (row < NN) op[(size_t)row*DD + col] = acc[mi][ni][r] + bs;
        }
    }
  }
  __syncthreads();
  // ---- K (keep in regs) ----
  stageB(&g_Wb[(size_t)(setbase+1)*DD*DD]);
  __syncthreads();
  computeC(accK);
  __syncthreads();
  // ---- V, then pack KV ----
  stageB(&g_Wb[(size_t)(setbase+2)*DD*DD]);
  __syncthreads();
  computeC(acc);
  {
    const float* bK = bp.b[conv*4+1];
    const float* bV = bp.b[conv*4+2];
#pragma unroll
    for (int ni=0;ni<2;++ni){
      int col = n0w + ni*16 + lrow;
      float bk = bK[col], bv = bV[col];
#pragma unroll
      for (int mi=0;mi<4;++mi)
#pragma unroll
        for (int r=0;r<4;++r){
          int row = m0 + mi*16 + kg*4 + r;
          if (row < NN){
            ushort2 kv;
            kv.x = f2bf(accK[mi][ni][r] + bk);
            kv.y = f2bf(acc [mi][ni][r] + bv);
            g_KV[conv][(size_t)row*DD + col] = kv;
          }
        }
    }
  }
  __syncthreads();
  // ---- S ----
  stageB(&g_Wb[(size_t)(setbase+3)*DD*DD]);
  __syncthreads();
  computeC(acc);
  {
    const float* bias = bp.b[conv*4+3];
    float* op = g_S[conv];
#pragma unroll
    for (int ni=0;ni<2;++ni){
      int col = n0w + ni*16 + lrow;
      float bs = bias[col];
#pragma unroll
      for (int mi=0;mi<4;++mi)
#pragma unroll
        for (int r=0;r<4;++r){
          int row = m0 + mi*16 + kg*4 + r;
          if (row < NN) op[(size_t)row*DD + col] = acc[mi][ni][r] + bs;
        }
    }
  }
}

// ---------- wave helpers ----------
__device__ inline float waveRed(float v){
  v += __shfl_xor(v,32); v += __shfl_xor(v,16); v += __shfl_xor(v,8);
  v += __shfl_xor(v,4);  v += __shfl_xor(v,2);  v += __shfl_xor(v,1);
  return v;
}
__device__ inline float headRed16(float v){   // sum over 16-lane group (one head, 2 ch/lane)
  v += __shfl_xor(v,8); v += __shfl_xor(v,4);
  v += __shfl_xor(v,2); v += __shfl_xor(v,1);
  return v;
}

// ---------- per-dst-node attention aggregation ----------
// grid (cdiv(NN,4), 2); block 256 = 4 independent waves (no barriers), one node per wave.
// Lane l holds channels 2l, 2l+1 (head = l>>4; 16-lane head groups). Folded edge-embedding.
__global__ __launch_bounds__(256) void k_agg(
    const float* __restrict__ WeT, const float* __restrict__ WeH,
    const float* __restrict__ Wt,  const float* __restrict__ bt4,
    const float* __restrict__ Wh,  const float* __restrict__ bh4){
  int conv = blockIdx.y;
  int wave = threadIdx.x >> 6;
  int lane = threadIdx.x & 63;
  int i = blockIdx.x*4 + wave;
  if (i >= NN) return;
  int d0 = lane*2;

  // per-channel edge-encoder coefficients for channels d0, d0+1
  float c0a=0.f,c1a=0.f,c2a=0.f,c3a=0.f;
  float c0b=0.f,c1b=0.f,c2b=0.f,c3b=0.f;
  if (conv==0){
#pragma unroll
    for (int j=0;j<4;++j){
      float wa=WeT[j*DD+d0], wb=WeT[j*DD+d0+1];
      c1a += Wt[j]*wa; c0a += bt4[j]*wa;
      c1b += Wt[j]*wb; c0b += bt4[j]*wb;
    }
  } else {
#pragma unroll
    for (int j=0;j<4;++j){
      float wa=WeH[j*DD+d0], wb=WeH[j*DD+d0+1];
      c0a += Wh[j]*wa; c1a += Wh[4+j]*wa; c2a += Wh[8+j]*wa; c3a += bh4[j]*wa;
      c0b += Wh[j]*wb; c1b += Wh[4+j]*wb; c2b += Wh[8+j]*wb; c3b += bh4[j]*wb;
    }
  }

  float2 q2 = *reinterpret_cast<const float2*>(&g_Q[conv][(size_t)i*DD+d0]);
  float q0 = q2.x, q1 = q2.y;
  // per-(node,head) scalars q.c_j (sum over the head's 32 channels)
  float qe0 = headRed16(q0*c0a + q1*c0b);
  float qe1 = headRed16(q0*c1a + q1*c1b);
  float qe2=0.f, qe3=0.f;
  if (conv==1){
    qe2 = headRed16(q0*c2a + q1*c2b);
    qe3 = headRed16(q0*c3a + q1*c3b);
  }

  const int*  srcc = g_srcc[conv];
  const uint2* KV  = reinterpret_cast<const uint2*>(g_KV[conv]);   // 2 channels per uint2... (4B each)
  int beg=g_rs[conv][i], end=g_rs[conv][i+1];
  int cnt = end-beg;

  const float inv32 = 0.17677669529663687f;   // 1/sqrt(32)
  float m=-INFINITY, den=0.f, ac0=0.f, ac1=0.f, x0=0.f, x1=0.f, x2=0.f;

  if (cnt>0){
    uint2 kv; float4 at=make_float4(0.f,0.f,0.f,0.f);
    {
      int s=srcc[beg];
      if (conv==0) at.x=g_ta[beg]; else at=g_ha[beg];
      kv = KV[(size_t)s*(DD/2)+lane];
    }
    for (int idx=beg; idx<end; ++idx){
      uint2 ckv=kv; float4 ca=at;
      if (idx+1<end){
        int s=srcc[idx+1];
        if (conv==0) at.x=g_ta[idx+1]; else at=g_ha[idx+1];
        kv = KV[(size_t)s*(DD/2)+lane];
      }
      float k0=bf_lo(ckv.x), v0=bf_hi(ckv.x);
      float k1=bf_lo(ckv.y), v1=bf_hi(ckv.y);
      float p = q0*k0 + q1*k1;
      p += __shfl_xor(p,8); p += __shfl_xor(p,4); p += __shfl_xor(p,2); p += __shfl_xor(p,1);
      float lg = (conv==0) ? (p + qe0 + ca.x*qe1)*inv32
                           : (p + ca.x*qe0 + ca.y*qe1 + ca.z*qe2 + qe3)*inv32;
      float nm = fmaxf(m,lg);
      float sc = __expf(m-nm);        // exp(-inf)=0 on first edge
      float ea = __expf(lg-nm);
      den = den*sc + ea;
      ac0 = ac0*sc + ea*v0;
      ac1 = ac1*sc + ea*v1;
      x0  = x0*sc + ea*ca.x;
      if (conv==1){ x1 = x1*sc + ea*ca.y; x2 = x2*sc + ea*ca.z; }
      m = nm;
    }
  }

  float r0, r1;
  if (cnt==0){
    r0 = 0.f; r1 = 0.f;
  } else {
    float id = 1.f/den;
    if (conv==0){
      float xm = x0*id;
      r0 = ac0*id + c0a + c1a*xm;
      r1 = ac1*id + c0b + c1b*xm;
    } else {
      float xm0=x0*id, xm1=x1*id, xm2=x2*id;
      r0 = ac0*id + c0a*xm0 + c1a*xm1 + c2a*xm2 + c3a;
      r1 = ac1*id + c0b*xm0 + c1b*xm1 + c2b*xm2 + c3b;
    }
  }
  float2 s2 = *reinterpret_cast<const float2*>(&g_S[conv][(size_t)i*DD+d0]);
  float* o = conv ? g_ho : g_to;
  float2 out2; out2.x = r0 + s2.x; out2.y = r1 + s2.y;
  *reinterpret_cast<float2*>(&o[(size_t)i*DD+d0]) = out2;
}

// g_h += silu(layernorm(g_to + g_ho)) ; one wave per node, 4 nodes per block
__global__ __launch_bounds__(256) void k_combine(const float* __restrict__ g, const float* __restrict__ bt){
  int lane = threadIdx.x & 63;
  int node = blockIdx.x*4 + (threadIdx.x>>6);
  if (node>=NN) return;
  size_t i0 = (size_t)node*DD + lane, i1 = i0+64;
  float v0 = g_to[i0] + g_ho[i0];
  float v1 = g_to[i1] + g_ho[i1];
  float s = waveRed(v0+v1);
  float mean = s*(1.f/128.f);
  float d0=v0-mean, d1=v1-mean;
  float q = waveRed(d0*d0+d1*d1);
  float inv = 1.f/sqrtf(q*(1.f/128.f)+1e-5f);
  float c0 = d0*inv*g[lane]+bt[lane];
  float c1 = d1*inv*g[lane+64]+bt[lane+64];
  float h0 = g_h[i0] + c0/(1.f+__expf(-c0));
  float h1 = g_h[i1] + c1/(1.f+__expf(-c1));
  g_h[i0] = h0; g_h[i1] = h1;
  g_hb[i0] = f2bf(h0); g_hb[i1] = f2bf(h1);
}

// in-place final layernorm on g_h
__global__ __launch_bounds__(256) void k_finalln(const float* __restrict__ g, const float* __restrict__ b){
  int lane = threadIdx.x & 63;
  int node = blockIdx.x*4 + (threadIdx.x>>6);
  if (node>=NN) return;
  size_t i0 = (size_t)node*DD + lane, i1 = i0+64;
  float v0 = g_h[i0], v1 = g_h[i1];
  float s = waveRed(v0+v1);
  float mean = s*(1.f/128.f);
  float d0=v0-mean, d1=v1-mean;
  float q = waveRed(d0*d0+d1*d1);
  float inv = 1.f/sqrtf(q*(1.f/128.f)+1e-5f);
  g_h[i0]=d0*inv*g[lane]+b[lane];
  g_h[i1]=d1*inv*g[lane+64]+b[lane+64];
}

// mlp head: out3 = LN(silu(g_h@W1+b1)) @ W2 + b2 ; 8 nodes per block
__global__ __launch_bounds__(128) void k_head(
      const float* __restrict__ W1, const float* __restrict__ b1,
      const float* __restrict__ g, const float* __restrict__ bt,
      const float* __restrict__ W2, const float* __restrict__ b2,
      float* __restrict__ out){
  int d = threadIdx.x;
  int wv = d >> 6;
  int i0 = blockIdx.x*8;
  const int n = NN;
  __shared__ float rows[8][DD];
  __shared__ float comb[2];
#pragma unroll
  for (int t=0;t<8;++t){
    int node = i0+t;
    rows[t][d] = (node<n)? g_h[(size_t)node*DD+d] : 0.f;
  }
  __syncthreads();
  float z[8];
  float b1d = b1[d];
#pragma unroll
  for (int t=0;t<8;++t) z[t]=b1d;
  for (int k=0;k<DD;++k){
    float w = W1[k*DD+d];
#pragma unroll
    for (int t=0;t<8;++t) z[t] += rows[t][k]*w;
  }
#pragma unroll
  for (int t=0;t<8;++t){ float v=z[t]; z[t] = v/(1.f+expf(-v)); }
  float gd=g[d], btd=bt[d];
  float w2a=W2[d*3+0], w2b=W2[d*3+1], w2c=W2[d*3+2];
  float b2a=b2[0], b2b=b2[1], b2c=b2[2];
  for (int t=0;t<8;++t){
    int node=i0+t;
    float zz=z[t];
    float s = waveRed(zz);
    if ((d&63)==0) comb[wv]=s;
    __syncthreads();
    float mean=(comb[0]+comb[1])*(1.f/128.f);
    __syncthreads();
    float dv=zz-mean;
    float q2 = waveRed(dv*dv);
    if ((d&63)==0) comb[wv]=q2;
    __syncthreads();
    float inv = 1.f/sqrtf((comb[0]+comb[1])*(1.f/128.f)+1e-5f);
    __syncthreads();
    float zn = dv*inv*gd+btd;
    float p0 = waveRed(zn*w2a);
    if ((d&63)==0) comb[wv]=p0;
    __syncthreads();
    float o0 = comb[0]+comb[1]+b2a;
    __syncthreads();
    float p1 = waveRed(zn*w2b);
    if ((d&63)==0) comb[wv]=p1;
    __syncthreads();
    float o1 = comb[0]+comb[1]+b2b;
    __syncthreads();
    float p2 = waveRed(zn*w2c);
    if ((d&63)==0) comb[wv]=p2;
    __syncthreads();
    float o2 = comb[0]+comb[1]+b2c;
    __syncthreads();
    if (d==0 && node<n){
      out[(size_t)node*3+0]=o0; out[(size_t)node*3+1]=o1; out[(size_t)node*3+2]=o2;
    }
  }
}

extern "C" void kernel_launch(void* const* d_in, const int* in_sizes, int n_in,
                              void* d_out, int out_size, void* d_ws, size_t ws_size,
                              hipStream_t stream){
  (void)in_sizes; (void)n_in; (void)out_size; (void)d_ws; (void)ws_size;
  const float* x    = (const float*)d_in[0];
  const int*   eit  = (const int*)d_in[1];
  const int*   eih  = (const int*)d_in[2];
  const float* eat  = (const float*)d_in[3];
  const float* eah  = (const float*)d_in[4];
  const float* W_te = (const float*)d_in[5];
  const float* b_te = (const float*)d_in[6];
  const float* W_he = (const float*)d_in[7];
  const float* b_he = (const float*)d_in[8];
  const float *Wq_t=(const float*)d_in[9],  *bq_t=(const float*)d_in[10];
  const float *Wk_t=(const float*)d_in[11], *bk_t=(const float*)d_in[12];
  const float *Wv_t=(const float*)d_in[13], *bv_t=(const float*)d_in[14];
  const float *We_t=(const float*)d_in[15];
  const float *Ws_t=(const float*)d_in[16], *bs_t=(const float*)d_in[17];
  const float *Wq_h=(const float*)d_in[18], *bq_h=(const float*)d_in[19];
  const float *Wk_h=(const float*)d_in[20], *bk_h=(const float*)d_in[21];
  const float *Wv_h=(const float*)d_in[22], *bv_h=(const float*)d_in[23];
  const float *We_h=(const float*)d_in[24];
  const float *Ws_h=(const float*)d_in[25], *bs_h=(const float*)d_in[26];
  const float *norm_g=(const float*)d_in[27], *norm_b=(const float*)d_in[28];
  const float *fg=(const float*)d_in[29], *fb=(const float*)d_in[30];
  const float *dW1=(const float*)d_in[31], *db1=(const float*)d_in[32];
  const float *dg=(const float*)d_in[33],  *dbt=(const float*)d_in[34];
  const float *dW2=(const float*)d_in[35], *db2=(const float*)d_in[36];
  const float *sW1=(const float*)d_in[37], *sb1=(const float*)d_in[38];
  const float *sg=(const float*)d_in[39],  *sbt=(const float*)d_in[40];
  const float *sW2=(const float*)d_in[41], *sb2=(const float*)d_in[42];
  float* outp = (float*)d_out;

  k_copy_h<<<cdiv(NN*DD/4,256),256,0,stream>>>(x);

  WPtrs wp;
  for (int l=0;l<NL;++l){
    wp.W[l*8+0]=Wq_t+(size_t)l*DD*DD; wp.W[l*8+1]=Wk_t+(size_t)l*DD*DD;
    wp.W[l*8+2]=Wv_t+(size_t)l*DD*DD; wp.W[l*8+3]=Ws_t+(size_t)l*DD*DD;
    wp.W[l*8+4]=Wq_h+(size_t)l*DD*DD; wp.W[l*8+5]=Wk_h+(size_t)l*DD*DD;
    wp.W[l*8+6]=Wv_h+(size_t)l*DD*DD; wp.W[l*8+7]=Ws_h+(size_t)l*DD*DD;
  }
  k_cvtw<<<dim3(64,24),256,0,stream>>>(wp);

  k_zero_cnt<<<dim3(cdiv(NN,256),2),256,0,stream>>>();
  k_hist<<<dim3(cdiv(ET_N,256),2),256,0,stream>>>(eit+ET_N, eih+EH_N);
  k_scan<<<dim3(1,2),1024,0,stream>>>();
  k_scatter<<<dim3(cdiv(ET_N,256),2),256,0,stream>>>(eit, eih, eat, eah);

  for (int l=0;l<NL;++l){
    BiasP bp;
    bp.b[0]=bq_t+(size_t)l*DD; bp.b[1]=bk_t+(size_t)l*DD;
    bp.b[2]=bv_t+(size_t)l*DD; bp.b[3]=bs_t+(size_t)l*DD;
    bp.b[4]=bq_h+(size_t)l*DD; bp.b[5]=bk_h+(size_t)l*DD;
    bp.b[6]=bv_h+(size_t)l*DD; bp.b[7]=bs_h+(size_t)l*DD;
    k_gemm_mfma<<<dim3(cdiv(NN,64),2),256,0,stream>>>(l, bp);
    k_agg<<<dim3(cdiv(NN,4),2),256,0,stream>>>(We_t+(size_t)l*4*DD, We_h+(size_t)l*4*DD,
                                               W_te, b_te, W_he, b_he);
    k_combine<<<cdiv(NN,4),256,0,stream>>>(norm_g+(size_t)l*DD, norm_b+(size_t)l*DD);
  }
  k_finalln<<<cdiv(NN,4),256,0,stream>>>(fg, fb);
  k_head<<<cdiv(NN,8),128,0,stream>>>(dW1, db1, dg, dbt, dW2, db2, outp);
  k_head<<<cdiv(NN,8),128,0,stream>>>(sW1, sb1, sg, sbt, sW2, sb2, outp+(size_t)NN*3);
}